// Round 13
// baseline (290.726 us; speedup 1.0000x reference)
//
#include <hip/hip_runtime.h>
#include <hip/hip_bf16.h>

typedef __attribute__((ext_vector_type(4))) float f32x4;
typedef __attribute__((ext_vector_type(8))) __bf16 bf16x8;
typedef __attribute__((ext_vector_type(4))) __bf16 bf16x4;

static __device__ __forceinline__ int swz_off(int row, int b) {
  return row * 128 + (b ^ ((row & 7) << 4));
}

static __device__ __forceinline__ void atomic_add_f32(float* p, float v) {
  asm volatile("global_atomic_add_f32 %0, %1, off" :: "v"(p), "v"(v) : "memory");
}

static __device__ __forceinline__ void gl16(const void* g, const void* l) {
  typedef __attribute__((address_space(1))) void* gas1;
  typedef __attribute__((address_space(3))) void* as3;
  __builtin_amdgcn_global_load_lds((gas1)g, (as3)l, 16, 0, 0);
}

static __device__ __forceinline__ bf16x8 cvt8(f32x4 lo, f32x4 hi4) {
  bf16x8 r;
  r[0] = (__bf16)lo.x; r[1] = (__bf16)lo.y; r[2] = (__bf16)lo.z; r[3] = (__bf16)lo.w;
  r[4] = (__bf16)hi4.x; r[5] = (__bf16)hi4.y; r[6] = (__bf16)hi4.z; r[7] = (__bf16)hi4.w;
  return r;
}

static __device__ __forceinline__ float hsum4(f32x4 v) {
  return (v.x + v.y) + (v.z + v.w);
}

// ---------------------------------------------------------------------------
// gstream v2 (round-6 verified champion): m97-style skinny-N GEMM, double-
// buffered LDS, ONE __syncthreads per K-step. C = A[M,K] (f32) * B[K,N]
// (BT bf16 k-contiguous). BM=32, BK=64, BN=NB*16. 256 threads = 4 waves 1x4
// in N. Staging via global_load_lds width=16, XOR swizzle pre-applied to the
// GLOBAL source (LDS dest linear); fragment ds_reads apply the same XOR.
// Loop: sync(drains tile-kt loads) -> stage(kt+1 -> buf^1) -> compute(buf).
// The next tile's loads are in flight during the whole compute phase.
// ATOMIC=1: f32 global-atomic epilogue (split-K). ATOMIC=0: direct bf16
// store C^T[n][8000] (SWAP only, splits must be 1).
// ROWSUM=1 (SWAP,ATOMIC): wave 0 accumulates per-row sums of A into
// C[128*8000 + m].
// ---------------------------------------------------------------------------
template<int NB, int SWAP, int ROWSUM, int ATOMIC>
__global__ __launch_bounds__(256)
void gstream(const float* __restrict__ A1, const float* __restrict__ A2,
             const __bf16* __restrict__ BT, void* __restrict__ Cv,
             int lda, int ldbt, int ldc, int nrb, int ktps, int mA) {
  static_assert(NB == 4 || NB == 8, "NB must be 4 or 8");
  constexpr int FN = NB / 4;                 // per-wave N fragments
  constexpr int BCH = NB * 2;                // B chunks of 1KB
  constexpr int PERW = (8 + BCH) / 4;        // gloads per wave per K-step
  constexpr int HALF = 8192 + NB * 2048;     // bytes per buffer
  __shared__ __align__(16) char lds[2 * HALF];
  const int tid = threadIdx.x, lane = tid & 63, wid = tid >> 6;
  const int r16 = lane & 15, hi = lane >> 4;
  const int wn = wid;                        // 1x4 wave grid in N
  const int bid = blockIdx.x;
  const int ks = bid / nrb, rb = bid - ks * nrb;
  int m0 = rb * 32;
  const float* A = A1;
  int noff = 0;
  if (m0 >= mA) { A = A2; m0 -= mA; noff = NB * 16; }
  const int k0 = ks * ktps * 64;

  // per-lane pre-swizzled global sources; wave-uniform LDS chunk offsets
  const char* gsrc[PERW];
  unsigned ldso[PERW];
#pragma unroll
  for (int j = 0; j < PERW; ++j) {
    if (j < 2) {                             // A chunks (8: rows 4c..4c+3)
      const int c = wid + j * 4;
      const int row = c * 4 + (lane >> 4);
      const unsigned sb = (unsigned)((lane & 15) * 16) ^ (unsigned)((row & 7) << 4);
      gsrc[j] = (const char*)(A + (size_t)(m0 + row) * lda + k0) + sb;
      ldso[j] = c * 1024;
    } else {                                 // B chunks (BCH: rows 8c..8c+7)
      const int c = wid + (j - 2) * 4;
      const int row = c * 8 + (lane >> 3);
      const unsigned sb = (unsigned)((lane & 7) * 16) ^ (unsigned)((row & 7) << 4);
      gsrc[j] = (const char*)(BT + (size_t)row * ldbt + k0) + sb;
      ldso[j] = 8192 + c * 1024;
    }
  }

  f32x4 acc[2][FN];
#pragma unroll
  for (int a = 0; a < 2; ++a)
#pragma unroll
    for (int b = 0; b < FN; ++b) acc[a][b] = (f32x4){0.f, 0.f, 0.f, 0.f};
  float rsum[2] = {0.f, 0.f};

  const unsigned swz = (unsigned)((r16 & 7) << 4);

  // prologue: stage tile 0 into buffer 0
#pragma unroll
  for (int j = 0; j < PERW; ++j)
    gl16(gsrc[j], lds + ldso[j]);

  for (int kt = 0; kt < ktps; ++kt) {
    const int cur = kt & 1;
    const unsigned boff = (unsigned)(cur * HALF);
    __syncthreads();                         // drains tile-kt loads + barrier
    if (kt + 1 < ktps) {                     // stage tile kt+1 into other buf
      const unsigned noffb = (unsigned)((cur ^ 1) * HALF);
#pragma unroll
      for (int j = 0; j < PERW; ++j)
        gl16(gsrc[j] + (size_t)(kt + 1) * (j < 2 ? 256 : 128), lds + noffb + ldso[j]);
    }
#pragma unroll
    for (int kk = 0; kk < 2; ++kk) {
      bf16x8 af[2];
#pragma unroll
      for (int f = 0; f < 2; ++f) {
        const int row = f * 16 + r16;
        const unsigned p = (unsigned)(kk * 128 + hi * 32) ^ swz;
        f32x4 lo = *(const f32x4*)(lds + boff + row * 256 + p);
        f32x4 h4 = *(const f32x4*)(lds + boff + row * 256 + (p ^ 16u));
        af[f] = cvt8(lo, h4);
        if constexpr (ROWSUM) {
          if (wid == 0) rsum[f] += hsum4(lo) + hsum4(h4);
        }
      }
      bf16x8 bq[FN];
#pragma unroll
      for (int b = 0; b < FN; ++b) {
        const int row = wn * (FN * 16) + b * 16 + r16;
        const unsigned p = (unsigned)(kk * 64 + hi * 16) ^ swz;
        bq[b] = *(const bf16x8*)(lds + boff + 8192 + row * 128 + p);
      }
#pragma unroll
      for (int a = 0; a < 2; ++a)
#pragma unroll
        for (int b = 0; b < FN; ++b) {
          if constexpr (SWAP)
            acc[a][b] = __builtin_amdgcn_mfma_f32_16x16x32_bf16(bq[b], af[a], acc[a][b], 0, 0, 0);
          else
            acc[a][b] = __builtin_amdgcn_mfma_f32_16x16x32_bf16(af[a], bq[b], acc[a][b], 0, 0, 0);
        }
    }
  }

  // ---- epilogue ----
#pragma unroll
  for (int a = 0; a < 2; ++a)
#pragma unroll
    for (int b = 0; b < FN; ++b)
#pragma unroll
      for (int r = 0; r < 4; ++r) {
        const float v = acc[a][b][r];
        if constexpr (SWAP) {
          const int n = noff + wn * (FN * 16) + b * 16 + hi * 4 + r;
          const int m = m0 + a * 16 + r16;
          if constexpr (ATOMIC)
            atomic_add_f32(&((float*)Cv)[(size_t)n * 8000 + m], v);
          else
            ((__bf16*)Cv)[(size_t)n * 8000 + m] = (__bf16)v;
        } else {
          const int m = m0 + a * 16 + hi * 4 + r;
          const int n = wn * (FN * 16) + b * 16 + r16;
          atomic_add_f32(&((float*)Cv)[(size_t)m * ldc + n], v);
        }
      }
  if constexpr (ROWSUM) {
    if (wid == 0) {
#pragma unroll
      for (int a = 0; a < 2; ++a) {
        float s = rsum[a];
        s += __shfl_xor(s, 16);
        s += __shfl_xor(s, 32);
        if (hi == 0) atomic_add_f32(&((float*)Cv)[(size_t)128 * 8000 + m0 + a * 16 + r16], s);
      }
    }
  }
}

// ---------------------------------------------------------------------------
// Tiled GEMM (LDS-staged, reg path) for small-K cases (h, PQ).
//  EPI: 0 = f32 store C[m*ldc+n] (non-swap), 3 = f32 store CT[n*8000+m] (swap)
// ---------------------------------------------------------------------------
template<int BM, int BN, int WM, int WN, int ADT, int SWAP, int EPI>
__global__ __launch_bounds__(WM * WN * 64)
void gemm_tpl(const void* __restrict__ Ap, const void* __restrict__ A2p,
              const __bf16* __restrict__ BT, void* __restrict__ o0,
              int lda, int ldbt, int ldc, int nmb, int nbn, int ktps, int mA) {
  constexpr int T = WM * WN * 64;
  constexpr int TM = BM / WM, TN = BN / WN;
  constexpr int FM = TM / 16, FN = TN / 16;
  __shared__ __align__(16) char lds[(BM + BN) * 128];
  const int tid = threadIdx.x;
  const int wgid = blockIdx.x;
  const int ks = wgid / (nmb * nbn);
  const int rem = wgid % (nmb * nbn);
  const int mb = rem / nbn, nb = rem % nbn;

  int m0 = mb * BM;
  const int n0 = nb * BN;
  const void* Asel = Ap;
  if (m0 >= mA) { Asel = A2p; m0 -= mA; }

  const int lane = tid & 63, wid = tid >> 6;
  const int wm = wid / WN, wn = wid % WN;
  const int r16 = lane & 15, hi = lane >> 4;

  f32x4 acc[FM][FN];
#pragma unroll
  for (int a = 0; a < FM; ++a)
#pragma unroll
    for (int b = 0; b < FN; ++b) acc[a][b] = (f32x4){0.f, 0.f, 0.f, 0.f};

  const int kt0 = ks * ktps;
  for (int kt = kt0; kt < kt0 + ktps; ++kt) {
    const int k0 = kt << 6;
    if constexpr (ADT == 0) {
      const float* Af = (const float*)Asel;
      for (int c = tid; c < BM * 16; c += T) {
        const int r = c >> 4, c4 = c & 15;
        f32x4 v = *(const f32x4*)(Af + (size_t)(m0 + r) * lda + k0 + c4 * 4);
        bf16x4 bv;
        bv.x = (__bf16)v.x; bv.y = (__bf16)v.y; bv.z = (__bf16)v.z; bv.w = (__bf16)v.w;
        *(bf16x4*)(lds + swz_off(r, c4 * 8)) = bv;
      }
    } else {
      const __bf16* Ab = (const __bf16*)Asel;
      for (int c = tid; c < BM * 8; c += T) {
        const int r = c >> 3, k8 = c & 7;
        bf16x8 v = *(const bf16x8*)(Ab + (size_t)(m0 + r) * lda + k0 + k8 * 8);
        *(bf16x8*)(lds + swz_off(r, k8 * 16)) = v;
      }
    }
    for (int c = tid; c < BN * 8; c += T) {
      const int n = c >> 3, k8 = c & 7;
      bf16x8 v = *(const bf16x8*)(BT + (size_t)(n0 + n) * ldbt + k0 + k8 * 8);
      *(bf16x8*)(lds + swz_off(BM + n, k8 * 16)) = v;
    }
    __syncthreads();
#pragma unroll
    for (int kk = 0; kk < 2; ++kk) {
      bf16x8 af[FM], bfv[FN];
#pragma unroll
      for (int f = 0; f < FM; ++f)
        af[f] = *(const bf16x8*)(lds + swz_off(wm * TM + f * 16 + r16, kk * 64 + hi * 16));
#pragma unroll
      for (int f = 0; f < FN; ++f)
        bfv[f] = *(const bf16x8*)(lds + swz_off(BM + wn * TN + f * 16 + r16, kk * 64 + hi * 16));
#pragma unroll
      for (int a = 0; a < FM; ++a)
#pragma unroll
        for (int b = 0; b < FN; ++b) {
          if constexpr (SWAP)
            acc[a][b] = __builtin_amdgcn_mfma_f32_16x16x32_bf16(bfv[b], af[a], acc[a][b], 0, 0, 0);
          else
            acc[a][b] = __builtin_amdgcn_mfma_f32_16x16x32_bf16(af[a], bfv[b], acc[a][b], 0, 0, 0);
        }
    }
    __syncthreads();
  }
#pragma unroll
  for (int a = 0; a < FM; ++a)
#pragma unroll
    for (int b = 0; b < FN; ++b)
#pragma unroll
      for (int r = 0; r < 4; ++r) {
        const float v = acc[a][b][r];
        if constexpr (!SWAP) {
          const int m = m0 + wm * TM + a * 16 + hi * 4 + r;
          const int n = n0 + wn * TN + b * 16 + r16;
          if constexpr (EPI == 0) ((float*)o0)[(size_t)m * ldc + n] = v;
        } else {
          const int n = n0 + wn * TN + b * 16 + hi * 4 + r;
          const int m = m0 + wm * TM + a * 16 + r16;
          if constexpr (EPI == 3) ((float*)o0)[(size_t)n * 8000 + m] = v;
        }
      }
}

// ---------------------------------------------------------------------------
// zero_kernel: vectorized zero fill (f32x4), grid-stride
// ---------------------------------------------------------------------------
__global__ __launch_bounds__(256) void zero_kernel(f32x4* __restrict__ p, int n) {
  const f32x4 z = (f32x4){0.f, 0.f, 0.f, 0.f};
  for (int i = blockIdx.x * 256 + threadIdx.x; i < n; i += gridDim.x * 256) p[i] = z;
}

// f32 -> bf16 flat convert (R1f -> R1T)
__global__ __launch_bounds__(256) void cvt_kernel(const float* __restrict__ in,
                                                  __bf16* __restrict__ out, int n4) {
  const int i = blockIdx.x * 256 + threadIdx.x;
  if (i >= n4) return;
  f32x4 v = ((const f32x4*)in)[i];
  bf16x4 b;
  b.x = (__bf16)v.x; b.y = (__bf16)v.y; b.z = (__bf16)v.z; b.w = (__bf16)v.w;
  ((bf16x4*)out)[i] = b;
}

// ---------------------------------------------------------------------------
// prep: weights -> bf16 transposed, block-diag disc matrix, loss=0
// ---------------------------------------------------------------------------
__global__ void prep_kernel(const float* __restrict__ w1, const float* __restrict__ w2,
                            const float* __restrict__ dw,
                            __bf16* __restrict__ W1bT, __bf16* __restrict__ W2bT,
                            __bf16* __restrict__ WdT, float* __restrict__ loss_out) {
  const int total = 65536 + 65536 + 16384;
  for (int i = blockIdx.x * blockDim.x + threadIdx.x; i < total; i += gridDim.x * blockDim.x) {
    if (i < 65536) {                       // W1bT[n][k] = w1[k][n], [64][1024]
      const int n = i >> 10, k = i & 1023;
      W1bT[i] = (__bf16)w1[k * 64 + n];
    } else if (i < 131072) {               // W2bT[n][k] = w2[k][n], [1024][64]
      const int j = i - 65536;
      const int n = j >> 6, k = j & 63;
      W2bT[j] = (__bf16)w2[k * 1024 + n];
    } else {                               // WdT block-diag(disc_w^T), [128][128]
      const int j = i - 131072;
      const int n = j >> 7, k = j & 127;
      float v = 0.f;
      if (n < 64 && k < 64) v = dw[k * 64 + n];
      else if (n >= 64 && k >= 64) v = dw[(k - 64) * 64 + (n - 64)];
      WdT[j] = (__bf16)v;
    }
  }
  if (blockIdx.x == 0 && threadIdx.x == 0) *loss_out = 0.f;
}

// ---------------------------------------------------------------------------
// fixup_S: SfT f32 [128][8000] -> ET bf16 (relu), ZbT bf16 (rows 0..63, raw),
// E bf16 [8000][128] (relu), hid f32 [8000][64] (raw)
// ---------------------------------------------------------------------------
__global__ __launch_bounds__(256)
void fixup_S(const float* __restrict__ SfT, __bf16* __restrict__ ET,
             __bf16* __restrict__ ZbT, __bf16* __restrict__ E,
             float* __restrict__ hid) {
  __shared__ float Lt[128][36];
  const int m0 = blockIdx.x * 32;
  const int tid = threadIdx.x;
  for (int c = tid; c < 128 * 8; c += 256) {
    const int n = c >> 3, j4 = c & 7;
    f32x4 v = *(const f32x4*)(SfT + (size_t)n * 8000 + m0 + j4 * 4);
    *(f32x4*)(&Lt[n][j4 * 4]) = v;
    bf16x4 rb;
    rb.x = (__bf16)fmaxf(v.x, 0.f); rb.y = (__bf16)fmaxf(v.y, 0.f);
    rb.z = (__bf16)fmaxf(v.z, 0.f); rb.w = (__bf16)fmaxf(v.w, 0.f);
    *(bf16x4*)(ET + (size_t)n * 8000 + m0 + j4 * 4) = rb;
    if (n < 64) {
      bf16x4 zb;
      zb.x = (__bf16)v.x; zb.y = (__bf16)v.y; zb.z = (__bf16)v.z; zb.w = (__bf16)v.w;
      *(bf16x4*)(ZbT + (size_t)n * 8000 + m0 + j4 * 4) = zb;
    }
  }
  __syncthreads();
  for (int c = tid; c < 32 * 16; c += 256) {   // hid[m][n], n 0..63
    const int mm = c >> 4, n4 = c & 15;
    f32x4 v;
    v.x = Lt[n4 * 4 + 0][mm]; v.y = Lt[n4 * 4 + 1][mm];
    v.z = Lt[n4 * 4 + 2][mm]; v.w = Lt[n4 * 4 + 3][mm];
    *(f32x4*)(hid + (size_t)(m0 + mm) * 64 + n4 * 4) = v;
  }
  for (int c = tid; c < 32 * 16; c += 256) {   // E[m][n], relu
    const int mm = c >> 4, n8 = c & 15;
    bf16x8 v;
#pragma unroll
    for (int j = 0; j < 8; ++j) v[j] = (__bf16)fmaxf(Lt[n8 * 8 + j][mm], 0.f);
    *(bf16x8*)(E + (size_t)(m0 + mm) * 128 + n8 * 8) = v;
  }
}

// ---------------------------------------------------------------------------
// final: per row m: rs = GNT[128][m]; per half: l2-normalize(GNT/rs), sigmoid,
// dot against P/Q columns from PQT; write ret / ret_a.
// ---------------------------------------------------------------------------
__global__ __launch_bounds__(64) void final_kernel(const float* __restrict__ GNT,
                                                   const float* __restrict__ PQT,
                                                   const float* __restrict__ bptr,
                                                   float* __restrict__ out_ret,
                                                   float* __restrict__ out_reta) {
  const int m = blockIdx.x * 64 + threadIdx.x;
  const float b = bptr[0];
  const float inv_rs = 1.f / GNT[(size_t)128 * 8000 + m];
  float r1 = 0, r2 = 0, ra1 = 0, ra2 = 0;
#pragma unroll
  for (int h = 0; h < 2; ++h) {
    float ss = 0.f;
    for (int n = 0; n < 64; ++n) {
      const float t = GNT[(size_t)(h * 64 + n) * 8000 + m] * inv_rs;
      ss += t * t;
    }
    float nrm = fmaxf(sqrtf(ss), 1e-12f);
    const float inv = inv_rs / nrm;
    float s_p = 0.f, s_q = 0.f;
    for (int n = 0; n < 64; ++n) {
      const float t = GNT[(size_t)(h * 64 + n) * 8000 + m] * inv;
      const float g = 1.f / (1.f + expf(-t));
      s_p += PQT[(size_t)n * 8000 + m] * g;
      s_q += PQT[(size_t)(64 + n) * 8000 + m] * g;
    }
    if (h == 0) { r1 = s_p + b; r2 = s_q + b; }
    else        { ra1 = s_q + b; ra2 = s_p + b; }
  }
  out_ret[m * 2] = r1;  out_ret[m * 2 + 1] = r2;
  out_reta[m * 2] = ra1; out_reta[m * 2 + 1] = ra2;
}

// ---------------------------------------------------------------------------
extern "C" void kernel_launch(void* const* d_in, const int* in_sizes, int n_in,
                              void* d_out, int out_size, void* d_ws, size_t ws_size,
                              hipStream_t stream) {
  const float* feat   = (const float*)d_in[0];
  const float* feat_a = (const float*)d_in[1];
  const float* adj    = (const float*)d_in[2];
  const float* gneigh = (const float*)d_in[3];
  const float* w1     = (const float*)d_in[4];
  const float* w2     = (const float*)d_in[5];
  const float* dw     = (const float*)d_in[6];
  const float* db     = (const float*)d_in[7];

  float* out      = (float*)d_out;
  float* out_hid  = out;                 // [8000,64]
  float* out_h    = out + 512000;        // [8000,1024]
  float* out_ret  = out + 8704000;       // [8000,2]
  float* out_reta = out + 8720000;       // [8000,2]
  float* out_loss = out + 8736000;       // scalar

  char* ws = (char*)d_ws;
  float*  SfT  = (float*) (ws);              // [128][8000] f32 atomic accum
  float*  PQT  = (float*) (ws);              // alias: reused after fixup_S
  float*  Yf   = (float*) (ws + 4096000);    // [8000][64] f32 atomic accum
  float*  GNTf = (float*) (ws + 6144000);    // [129][8000] f32 accum (row128=rowsum)
  float*  R1f  = (float*) (ws + 10272000);   // [128][8000] f32 atomic accum
  __bf16* E    = (__bf16*)(ws + 14368000);   // [8000][128] bf16
  __bf16* R1T  = (__bf16*)(ws + 16416000);   // [128][8000] bf16
  __bf16* ET   = (__bf16*)(ws + 18464000);   // [128][8000] bf16 (relu'd)
  __bf16* ZbT  = (__bf16*)(ws + 20512000);   // [64][8000] bf16
  __bf16* WdT  = (__bf16*)(ws + 21536000);   // [128][128]
  __bf16* W1bT = (__bf16*)(ws + 21568768);   // [64][1024]
  __bf16* W2bT = (__bf16*)(ws + 21699840);   // [1024][64]

  const int BIG = 1 << 30;

  // zero atomic accumulators (SfT, Yf, GNTf, R1f = first 14,368,000 bytes)
  zero_kernel<<<2048, 256, 0, stream>>>((f32x4*)ws, 898000);
  prep_kernel<<<256, 256, 0, stream>>>(w1, w2, dw, W1bT, W2bT, WdT, out_loss);

  // R1f += ([feat;feat_a] @ W1)^T  M=16000 K=1024 N=64, splits=4 (atomic)
  gstream<4, 1, 0, 1><<<2000, 256, 0, stream>>>(
      feat, feat_a, W1bT, R1f, 1024, 1024, 0, 500, 4, 8000);
  cvt_kernel<<<1000, 256, 0, stream>>>(R1f, R1T, 256000);

  // SfT += (adj @ [fw1|fa1])^T      M=8000 K=8000 N=128, splits=5
  gstream<8, 1, 0, 1><<<1250, 256, 0, stream>>>(
      adj, adj, R1T, SfT, 8000, 8000, 0, 250, 25, BIG);

  fixup_S<<<250, 256, 0, stream>>>(SfT, ET, ZbT, E, out_hid);

  // Yf += adj @ z                   M=8000 K=8000 N=64, splits=5, row-major
  gstream<4, 0, 0, 1><<<1250, 256, 0, stream>>>(
      adj, adj, ZbT, Yf, 8000, 8000, 64, 250, 25, BIG);

  // h = Yf @ W2                     M=8000 K=64 N=1024, direct f32
  gemm_tpl<64, 128, 2, 2, 0, 0, 0><<<1000, 256, 0, stream>>>(
      Yf, Yf, W2bT, out_h, 64, 64, 1024, 125, 8, 1, BIG);

  // GNTf += (graph_neigh @ [emb|emb_a])^T + rowsums  M=8000 K=8000 N=128
  gstream<8, 1, 1, 1><<<1250, 256, 0, stream>>>(
      gneigh, gneigh, ET, GNTf, 8000, 8000, 0, 250, 25, BIG);

  // PQT = (E @ blockdiag(disc_w))^T  M=8000 K=128 N=128, direct f32
  gemm_tpl<16, 128, 1, 4, 1, 1, 3><<<500, 256, 0, stream>>>(
      E, E, WdT, PQT, 128, 128, 0, 500, 1, 2, BIG);

  final_kernel<<<125, 64, 0, stream>>>(GNTf, PQT, db, out_ret, out_reta);
}

// Round 14
// 280.091 us; speedup vs baseline: 1.0380x; 1.0380x over previous
//
#include <hip/hip_runtime.h>
#include <hip/hip_bf16.h>

typedef __attribute__((ext_vector_type(4))) float f32x4;
typedef __attribute__((ext_vector_type(8))) __bf16 bf16x8;
typedef __attribute__((ext_vector_type(4))) __bf16 bf16x4;

static __device__ __forceinline__ int swz_off(int row, int b) {
  return row * 128 + (b ^ ((row & 7) << 4));
}

static __device__ __forceinline__ void atomic_add_f32(float* p, float v) {
  asm volatile("global_atomic_add_f32 %0, %1, off" :: "v"(p), "v"(v) : "memory");
}

static __device__ __forceinline__ void gl16(const void* g, const void* l) {
  typedef __attribute__((address_space(1))) void* gas1;
  typedef __attribute__((address_space(3))) void* as3;
  __builtin_amdgcn_global_load_lds((gas1)g, (as3)l, 16, 0, 0);
}

static __device__ __forceinline__ bf16x8 cvt8(f32x4 lo, f32x4 hi4) {
  bf16x8 r;
  r[0] = (__bf16)lo.x; r[1] = (__bf16)lo.y; r[2] = (__bf16)lo.z; r[3] = (__bf16)lo.w;
  r[4] = (__bf16)hi4.x; r[5] = (__bf16)hi4.y; r[6] = (__bf16)hi4.z; r[7] = (__bf16)hi4.w;
  return r;
}

static __device__ __forceinline__ float hsum4(f32x4 v) {
  return (v.x + v.y) + (v.z + v.w);
}

// ---------------------------------------------------------------------------
// gstream v2 (round-6 verified champion): m97-style skinny-N GEMM, double-
// buffered LDS, ONE __syncthreads per K-step. C = A[M,K] (f32) * B[K,N]
// (BT bf16 k-contiguous). BM=32, BK=64, BN=NB*16. 256 threads = 4 waves 1x4
// in N. Staging via global_load_lds width=16, XOR swizzle pre-applied to the
// GLOBAL source (LDS dest linear); fragment ds_reads apply the same XOR.
// Loop: sync(drains tile-kt loads) -> stage(kt+1 -> buf^1) -> compute(buf).
// The next tile's loads are in flight during the whole compute phase.
// ATOMIC=1: f32 global-atomic epilogue (split-K). ATOMIC=0: direct bf16
// store C^T[n][8000] (SWAP only, splits must be 1).
// ROWSUM=1 (SWAP,ATOMIC): wave 0 accumulates per-row sums of A into
// C[128*8000 + m].
// ---------------------------------------------------------------------------
template<int NB, int SWAP, int ROWSUM, int ATOMIC>
__global__ __launch_bounds__(256)
void gstream(const float* __restrict__ A1, const float* __restrict__ A2,
             const __bf16* __restrict__ BT, void* __restrict__ Cv,
             int lda, int ldbt, int ldc, int nrb, int ktps, int mA) {
  static_assert(NB == 4 || NB == 8, "NB must be 4 or 8");
  constexpr int FN = NB / 4;                 // per-wave N fragments
  constexpr int BCH = NB * 2;                // B chunks of 1KB
  constexpr int PERW = (8 + BCH) / 4;        // gloads per wave per K-step
  constexpr int HALF = 8192 + NB * 2048;     // bytes per buffer
  __shared__ __align__(16) char lds[2 * HALF];
  const int tid = threadIdx.x, lane = tid & 63, wid = tid >> 6;
  const int r16 = lane & 15, hi = lane >> 4;
  const int wn = wid;                        // 1x4 wave grid in N
  const int bid = blockIdx.x;
  const int ks = bid / nrb, rb = bid - ks * nrb;
  int m0 = rb * 32;
  const float* A = A1;
  int noff = 0;
  if (m0 >= mA) { A = A2; m0 -= mA; noff = NB * 16; }
  const int k0 = ks * ktps * 64;

  // per-lane pre-swizzled global sources; wave-uniform LDS chunk offsets
  const char* gsrc[PERW];
  unsigned ldso[PERW];
#pragma unroll
  for (int j = 0; j < PERW; ++j) {
    if (j < 2) {                             // A chunks (8: rows 4c..4c+3)
      const int c = wid + j * 4;
      const int row = c * 4 + (lane >> 4);
      const unsigned sb = (unsigned)((lane & 15) * 16) ^ (unsigned)((row & 7) << 4);
      gsrc[j] = (const char*)(A + (size_t)(m0 + row) * lda + k0) + sb;
      ldso[j] = c * 1024;
    } else {                                 // B chunks (BCH: rows 8c..8c+7)
      const int c = wid + (j - 2) * 4;
      const int row = c * 8 + (lane >> 3);
      const unsigned sb = (unsigned)((lane & 7) * 16) ^ (unsigned)((row & 7) << 4);
      gsrc[j] = (const char*)(BT + (size_t)row * ldbt + k0) + sb;
      ldso[j] = 8192 + c * 1024;
    }
  }

  f32x4 acc[2][FN];
#pragma unroll
  for (int a = 0; a < 2; ++a)
#pragma unroll
    for (int b = 0; b < FN; ++b) acc[a][b] = (f32x4){0.f, 0.f, 0.f, 0.f};
  float rsum[2] = {0.f, 0.f};

  const unsigned swz = (unsigned)((r16 & 7) << 4);

  // prologue: stage tile 0 into buffer 0
#pragma unroll
  for (int j = 0; j < PERW; ++j)
    gl16(gsrc[j], lds + ldso[j]);

  for (int kt = 0; kt < ktps; ++kt) {
    const int cur = kt & 1;
    const unsigned boff = (unsigned)(cur * HALF);
    __syncthreads();                         // drains tile-kt loads + barrier
    if (kt + 1 < ktps) {                     // stage tile kt+1 into other buf
      const unsigned noffb = (unsigned)((cur ^ 1) * HALF);
#pragma unroll
      for (int j = 0; j < PERW; ++j)
        gl16(gsrc[j] + (size_t)(kt + 1) * (j < 2 ? 256 : 128), lds + noffb + ldso[j]);
    }
#pragma unroll
    for (int kk = 0; kk < 2; ++kk) {
      bf16x8 af[2];
#pragma unroll
      for (int f = 0; f < 2; ++f) {
        const int row = f * 16 + r16;
        const unsigned p = (unsigned)(kk * 128 + hi * 32) ^ swz;
        f32x4 lo = *(const f32x4*)(lds + boff + row * 256 + p);
        f32x4 h4 = *(const f32x4*)(lds + boff + row * 256 + (p ^ 16u));
        af[f] = cvt8(lo, h4);
        if constexpr (ROWSUM) {
          if (wid == 0) rsum[f] += hsum4(lo) + hsum4(h4);
        }
      }
      bf16x8 bq[FN];
#pragma unroll
      for (int b = 0; b < FN; ++b) {
        const int row = wn * (FN * 16) + b * 16 + r16;
        const unsigned p = (unsigned)(kk * 64 + hi * 16) ^ swz;
        bq[b] = *(const bf16x8*)(lds + boff + 8192 + row * 128 + p);
      }
#pragma unroll
      for (int a = 0; a < 2; ++a)
#pragma unroll
        for (int b = 0; b < FN; ++b) {
          if constexpr (SWAP)
            acc[a][b] = __builtin_amdgcn_mfma_f32_16x16x32_bf16(bq[b], af[a], acc[a][b], 0, 0, 0);
          else
            acc[a][b] = __builtin_amdgcn_mfma_f32_16x16x32_bf16(af[a], bq[b], acc[a][b], 0, 0, 0);
        }
    }
  }

  // ---- epilogue ----
#pragma unroll
  for (int a = 0; a < 2; ++a)
#pragma unroll
    for (int b = 0; b < FN; ++b)
#pragma unroll
      for (int r = 0; r < 4; ++r) {
        const float v = acc[a][b][r];
        if constexpr (SWAP) {
          const int n = noff + wn * (FN * 16) + b * 16 + hi * 4 + r;
          const int m = m0 + a * 16 + r16;
          if constexpr (ATOMIC)
            atomic_add_f32(&((float*)Cv)[(size_t)n * 8000 + m], v);
          else
            ((__bf16*)Cv)[(size_t)n * 8000 + m] = (__bf16)v;
        } else {
          const int m = m0 + a * 16 + hi * 4 + r;
          const int n = wn * (FN * 16) + b * 16 + r16;
          atomic_add_f32(&((float*)Cv)[(size_t)m * ldc + n], v);
        }
      }
  if constexpr (ROWSUM) {
    if (wid == 0) {
#pragma unroll
      for (int a = 0; a < 2; ++a) {
        float s = rsum[a];
        s += __shfl_xor(s, 16);
        s += __shfl_xor(s, 32);
        if (hi == 0) atomic_add_f32(&((float*)Cv)[(size_t)128 * 8000 + m0 + a * 16 + r16], s);
      }
    }
  }
}

// ---------------------------------------------------------------------------
// Tiled GEMM (LDS-staged, reg path) for small-K cases (h, PQ).
//  EPI: 0 = f32 store C[m*ldc+n] (non-swap), 3 = f32 store CT[n*8000+m] (swap)
// ---------------------------------------------------------------------------
template<int BM, int BN, int WM, int WN, int ADT, int SWAP, int EPI>
__global__ __launch_bounds__(WM * WN * 64)
void gemm_tpl(const void* __restrict__ Ap, const void* __restrict__ A2p,
              const __bf16* __restrict__ BT, void* __restrict__ o0,
              int lda, int ldbt, int ldc, int nmb, int nbn, int ktps, int mA) {
  constexpr int T = WM * WN * 64;
  constexpr int TM = BM / WM, TN = BN / WN;
  constexpr int FM = TM / 16, FN = TN / 16;
  __shared__ __align__(16) char lds[(BM + BN) * 128];
  const int tid = threadIdx.x;
  const int wgid = blockIdx.x;
  const int ks = wgid / (nmb * nbn);
  const int rem = wgid % (nmb * nbn);
  const int mb = rem / nbn, nb = rem % nbn;

  int m0 = mb * BM;
  const int n0 = nb * BN;
  const void* Asel = Ap;
  if (m0 >= mA) { Asel = A2p; m0 -= mA; }

  const int lane = tid & 63, wid = tid >> 6;
  const int wm = wid / WN, wn = wid % WN;
  const int r16 = lane & 15, hi = lane >> 4;

  f32x4 acc[FM][FN];
#pragma unroll
  for (int a = 0; a < FM; ++a)
#pragma unroll
    for (int b = 0; b < FN; ++b) acc[a][b] = (f32x4){0.f, 0.f, 0.f, 0.f};

  const int kt0 = ks * ktps;
  for (int kt = kt0; kt < kt0 + ktps; ++kt) {
    const int k0 = kt << 6;
    if constexpr (ADT == 0) {
      const float* Af = (const float*)Asel;
      for (int c = tid; c < BM * 16; c += T) {
        const int r = c >> 4, c4 = c & 15;
        f32x4 v = *(const f32x4*)(Af + (size_t)(m0 + r) * lda + k0 + c4 * 4);
        bf16x4 bv;
        bv.x = (__bf16)v.x; bv.y = (__bf16)v.y; bv.z = (__bf16)v.z; bv.w = (__bf16)v.w;
        *(bf16x4*)(lds + swz_off(r, c4 * 8)) = bv;
      }
    } else {
      const __bf16* Ab = (const __bf16*)Asel;
      for (int c = tid; c < BM * 8; c += T) {
        const int r = c >> 3, k8 = c & 7;
        bf16x8 v = *(const bf16x8*)(Ab + (size_t)(m0 + r) * lda + k0 + k8 * 8);
        *(bf16x8*)(lds + swz_off(r, k8 * 16)) = v;
      }
    }
    for (int c = tid; c < BN * 8; c += T) {
      const int n = c >> 3, k8 = c & 7;
      bf16x8 v = *(const bf16x8*)(BT + (size_t)(n0 + n) * ldbt + k0 + k8 * 8);
      *(bf16x8*)(lds + swz_off(BM + n, k8 * 16)) = v;
    }
    __syncthreads();
#pragma unroll
    for (int kk = 0; kk < 2; ++kk) {
      bf16x8 af[FM], bfv[FN];
#pragma unroll
      for (int f = 0; f < FM; ++f)
        af[f] = *(const bf16x8*)(lds + swz_off(wm * TM + f * 16 + r16, kk * 64 + hi * 16));
#pragma unroll
      for (int f = 0; f < FN; ++f)
        bfv[f] = *(const bf16x8*)(lds + swz_off(BM + wn * TN + f * 16 + r16, kk * 64 + hi * 16));
#pragma unroll
      for (int a = 0; a < FM; ++a)
#pragma unroll
        for (int b = 0; b < FN; ++b) {
          if constexpr (SWAP)
            acc[a][b] = __builtin_amdgcn_mfma_f32_16x16x32_bf16(bfv[b], af[a], acc[a][b], 0, 0, 0);
          else
            acc[a][b] = __builtin_amdgcn_mfma_f32_16x16x32_bf16(af[a], bfv[b], acc[a][b], 0, 0, 0);
        }
    }
    __syncthreads();
  }
#pragma unroll
  for (int a = 0; a < FM; ++a)
#pragma unroll
    for (int b = 0; b < FN; ++b)
#pragma unroll
      for (int r = 0; r < 4; ++r) {
        const float v = acc[a][b][r];
        if constexpr (!SWAP) {
          const int m = m0 + wm * TM + a * 16 + hi * 4 + r;
          const int n = n0 + wn * TN + b * 16 + r16;
          if constexpr (EPI == 0) ((float*)o0)[(size_t)m * ldc + n] = v;
        } else {
          const int n = n0 + wn * TN + b * 16 + hi * 4 + r;
          const int m = m0 + wm * TM + a * 16 + r16;
          if constexpr (EPI == 3) ((float*)o0)[(size_t)n * 8000 + m] = v;
        }
      }
}

// ---------------------------------------------------------------------------
// zero_kernel: vectorized zero fill (f32x4), grid-stride
// ---------------------------------------------------------------------------
__global__ __launch_bounds__(256) void zero_kernel(f32x4* __restrict__ p, int n) {
  const f32x4 z = (f32x4){0.f, 0.f, 0.f, 0.f};
  for (int i = blockIdx.x * 256 + threadIdx.x; i < n; i += gridDim.x * 256) p[i] = z;
}

// ---------------------------------------------------------------------------
// prep: weights -> bf16 transposed, block-diag disc matrix, loss=0
// ---------------------------------------------------------------------------
__global__ void prep_kernel(const float* __restrict__ w1, const float* __restrict__ w2,
                            const float* __restrict__ dw,
                            __bf16* __restrict__ W1bT, __bf16* __restrict__ W2bT,
                            __bf16* __restrict__ WdT, float* __restrict__ loss_out) {
  const int total = 65536 + 65536 + 16384;
  for (int i = blockIdx.x * blockDim.x + threadIdx.x; i < total; i += gridDim.x * blockDim.x) {
    if (i < 65536) {                       // W1bT[n][k] = w1[k][n], [64][1024]
      const int n = i >> 10, k = i & 1023;
      W1bT[i] = (__bf16)w1[k * 64 + n];
    } else if (i < 131072) {               // W2bT[n][k] = w2[k][n], [1024][64]
      const int j = i - 65536;
      const int n = j >> 6, k = j & 63;
      W2bT[j] = (__bf16)w2[k * 1024 + n];
    } else {                               // WdT block-diag(disc_w^T), [128][128]
      const int j = i - 131072;
      const int n = j >> 7, k = j & 127;
      float v = 0.f;
      if (n < 64 && k < 64) v = dw[k * 64 + n];
      else if (n >= 64 && k >= 64) v = dw[(k - 64) * 64 + (n - 64)];
      WdT[j] = (__bf16)v;
    }
  }
  if (blockIdx.x == 0 && threadIdx.x == 0) *loss_out = 0.f;
}

// ---------------------------------------------------------------------------
// fixup_S: SfT f32 [128][8000] -> ET bf16 (relu), ZbT bf16 (rows 0..63, raw),
// E bf16 [8000][128] (relu), hid f32 [8000][64] (raw)
// ---------------------------------------------------------------------------
__global__ __launch_bounds__(256)
void fixup_S(const float* __restrict__ SfT, __bf16* __restrict__ ET,
             __bf16* __restrict__ ZbT, __bf16* __restrict__ E,
             float* __restrict__ hid) {
  __shared__ float Lt[128][36];
  const int m0 = blockIdx.x * 32;
  const int tid = threadIdx.x;
  for (int c = tid; c < 128 * 8; c += 256) {
    const int n = c >> 3, j4 = c & 7;
    f32x4 v = *(const f32x4*)(SfT + (size_t)n * 8000 + m0 + j4 * 4);
    *(f32x4*)(&Lt[n][j4 * 4]) = v;
    bf16x4 rb;
    rb.x = (__bf16)fmaxf(v.x, 0.f); rb.y = (__bf16)fmaxf(v.y, 0.f);
    rb.z = (__bf16)fmaxf(v.z, 0.f); rb.w = (__bf16)fmaxf(v.w, 0.f);
    *(bf16x4*)(ET + (size_t)n * 8000 + m0 + j4 * 4) = rb;
    if (n < 64) {
      bf16x4 zb;
      zb.x = (__bf16)v.x; zb.y = (__bf16)v.y; zb.z = (__bf16)v.z; zb.w = (__bf16)v.w;
      *(bf16x4*)(ZbT + (size_t)n * 8000 + m0 + j4 * 4) = zb;
    }
  }
  __syncthreads();
  for (int c = tid; c < 32 * 16; c += 256) {   // hid[m][n], n 0..63
    const int mm = c >> 4, n4 = c & 15;
    f32x4 v;
    v.x = Lt[n4 * 4 + 0][mm]; v.y = Lt[n4 * 4 + 1][mm];
    v.z = Lt[n4 * 4 + 2][mm]; v.w = Lt[n4 * 4 + 3][mm];
    *(f32x4*)(hid + (size_t)(m0 + mm) * 64 + n4 * 4) = v;
  }
  for (int c = tid; c < 32 * 16; c += 256) {   // E[m][n], relu
    const int mm = c >> 4, n8 = c & 15;
    bf16x8 v;
#pragma unroll
    for (int j = 0; j < 8; ++j) v[j] = (__bf16)fmaxf(Lt[n8 * 8 + j][mm], 0.f);
    *(bf16x8*)(E + (size_t)(m0 + mm) * 128 + n8 * 8) = v;
  }
}

// ---------------------------------------------------------------------------
// final: per row m: rs = GNT[128][m]; per half: l2-normalize(GNT/rs), sigmoid,
// dot against P/Q columns from PQT; write ret / ret_a.
// ---------------------------------------------------------------------------
__global__ __launch_bounds__(64) void final_kernel(const float* __restrict__ GNT,
                                                   const float* __restrict__ PQT,
                                                   const float* __restrict__ bptr,
                                                   float* __restrict__ out_ret,
                                                   float* __restrict__ out_reta) {
  const int m = blockIdx.x * 64 + threadIdx.x;
  const float b = bptr[0];
  const float inv_rs = 1.f / GNT[(size_t)128 * 8000 + m];
  float r1 = 0, r2 = 0, ra1 = 0, ra2 = 0;
#pragma unroll
  for (int h = 0; h < 2; ++h) {
    float ss = 0.f;
    for (int n = 0; n < 64; ++n) {
      const float t = GNT[(size_t)(h * 64 + n) * 8000 + m] * inv_rs;
      ss += t * t;
    }
    float nrm = fmaxf(sqrtf(ss), 1e-12f);
    const float inv = inv_rs / nrm;
    float s_p = 0.f, s_q = 0.f;
    for (int n = 0; n < 64; ++n) {
      const float t = GNT[(size_t)(h * 64 + n) * 8000 + m] * inv;
      const float g = 1.f / (1.f + expf(-t));
      s_p += PQT[(size_t)n * 8000 + m] * g;
      s_q += PQT[(size_t)(64 + n) * 8000 + m] * g;
    }
    if (h == 0) { r1 = s_p + b; r2 = s_q + b; }
    else        { ra1 = s_q + b; ra2 = s_p + b; }
  }
  out_ret[m * 2] = r1;  out_ret[m * 2 + 1] = r2;
  out_reta[m * 2] = ra1; out_reta[m * 2 + 1] = ra2;
}

// ---------------------------------------------------------------------------
extern "C" void kernel_launch(void* const* d_in, const int* in_sizes, int n_in,
                              void* d_out, int out_size, void* d_ws, size_t ws_size,
                              hipStream_t stream) {
  const float* feat   = (const float*)d_in[0];
  const float* feat_a = (const float*)d_in[1];
  const float* adj    = (const float*)d_in[2];
  const float* gneigh = (const float*)d_in[3];
  const float* w1     = (const float*)d_in[4];
  const float* w2     = (const float*)d_in[5];
  const float* dw     = (const float*)d_in[6];
  const float* db     = (const float*)d_in[7];

  float* out      = (float*)d_out;
  float* out_hid  = out;                 // [8000,64]
  float* out_h    = out + 512000;        // [8000,1024]
  float* out_ret  = out + 8704000;       // [8000,2]
  float* out_reta = out + 8720000;       // [8000,2]
  float* out_loss = out + 8736000;       // scalar

  char* ws = (char*)d_ws;
  float*  SfT  = (float*) (ws);              // [128][8000] f32 atomic accum
  float*  PQT  = (float*) (ws);              // alias: reused after fixup_S
  float*  Yf   = (float*) (ws + 4096000);    // [8000][64] f32 atomic accum
  float*  GNTf = (float*) (ws + 6144000);    // [129][8000] f32 accum (row128=rowsum)
  __bf16* E    = (__bf16*)(ws + 10272000);   // [8000][128] bf16
  __bf16* R1T  = (__bf16*)(ws + 12320000);   // [128][8000] bf16
  __bf16* ET   = (__bf16*)(ws + 14368000);   // [128][8000] bf16 (relu'd)
  __bf16* ZbT  = (__bf16*)(ws + 16416000);   // [64][8000] bf16
  __bf16* WdT  = (__bf16*)(ws + 17440000);   // [128][128]
  __bf16* W1bT = (__bf16*)(ws + 17472768);   // [64][1024]
  __bf16* W2bT = (__bf16*)(ws + 17603840);   // [1024][64]

  const int BIG = 1 << 30;

  // zero atomic accumulators (SfT, Yf, GNTf = first 10,272,000 bytes)
  zero_kernel<<<2048, 256, 0, stream>>>((f32x4*)ws, 642000);
  prep_kernel<<<256, 256, 0, stream>>>(w1, w2, dw, W1bT, W2bT, WdT, out_loss);

  // R1T = ([feat;feat_a] @ W1)^T   M=16000 K=1024 N=64, splits=1, direct bf16
  gstream<4, 1, 0, 0><<<500, 256, 0, stream>>>(
      feat, feat_a, W1bT, R1T, 1024, 1024, 0, 500, 16, 8000);

  // SfT += (adj @ [fw1|fa1])^T      M=8000 K=8000 N=128, splits=5
  gstream<8, 1, 0, 1><<<1250, 256, 0, stream>>>(
      adj, adj, R1T, SfT, 8000, 8000, 0, 250, 25, BIG);

  fixup_S<<<250, 256, 0, stream>>>(SfT, ET, ZbT, E, out_hid);

  // Yf += adj @ z                   M=8000 K=8000 N=64, splits=5, row-major
  gstream<4, 0, 0, 1><<<1250, 256, 0, stream>>>(
      adj, adj, ZbT, Yf, 8000, 8000, 64, 250, 25, BIG);

  // h = Yf @ W2                     M=8000 K=64 N=1024, direct f32
  gemm_tpl<64, 128, 2, 2, 0, 0, 0><<<1000, 256, 0, stream>>>(
      Yf, Yf, W2bT, out_h, 64, 64, 1024, 125, 8, 1, BIG);

  // GNTf += (graph_neigh @ [emb|emb_a])^T + rowsums  M=8000 K=8000 N=128
  gstream<8, 1, 1, 1><<<1250, 256, 0, stream>>>(
      gneigh, gneigh, ET, GNTf, 8000, 8000, 0, 250, 25, BIG);

  // PQT = (E @ blockdiag(disc_w))^T  M=8000 K=128 N=128, direct f32
  gemm_tpl<16, 128, 1, 4, 1, 1, 3><<<500, 256, 0, stream>>>(
      E, E, WdT, PQT, 128, 128, 0, 500, 1, 2, BIG);

  final_kernel<<<125, 64, 0, stream>>>(GNTf, PQT, db, out_ret, out_reta);
}